// Round 9
// baseline (341.511 us; speedup 1.0000x reference)
//
#include <hip/hip_runtime.h>
#include <hip/hip_bf16.h>

#define HW 3136
#define HH 56
#define WW 56
#define BB 4
#define CC 256
#define HD 128

// attention tile geometry
#define TH 4
#define TW 8
#define WR 8    // TH+4
#define WC 12   // TW+4
#define WPX 96  // WR*WC
#define KSTR2 136   // shorts per window pixel in LDS (128 + 8 pad, 16B-aligned)
#define RSTR 132    // floats per rel row

// MFMA GEMM geometry: 128x128 tile, BK=64, LDS row = 64 bf16 + pad -> 72 (144 B)
#define ASTR 72

typedef __attribute__((ext_vector_type(8))) short bf16x8;
typedef __attribute__((ext_vector_type(4))) float f32x4;

__device__ __forceinline__ unsigned short f2bf(float f) {
    unsigned int u; __builtin_memcpy(&u, &f, 4);
    unsigned int r = u + 0x7FFFu + ((u >> 16) & 1u);   // RNE
    return (unsigned short)(r >> 16);
}
__device__ __forceinline__ float bflo(unsigned int u) {
    unsigned int x = u << 16; float f; __builtin_memcpy(&f, &x, 4); return f;
}
__device__ __forceinline__ float bfhi(unsigned int u) {
    unsigned int x = u & 0xFFFF0000u; float f; __builtin_memcpy(&f, &x, 4); return f;
}

// ---------------- K0a: x [b][c][p] fp32 -> xt [(b*HW+p)][c] bf16 -------------
__global__ __launch_bounds__(256) void xt_cvt(const float* __restrict__ x,
                                              unsigned short* __restrict__ xt)
{
    int b = blockIdx.z;
    int c0 = blockIdx.y * 64;
    int p0 = blockIdx.x * 64;
    __shared__ float tile[64][65];   // [channel][pixel]
    int t = threadIdx.x;
    int p4 = t & 15, cl = t >> 4;
    const float* xb = x + ((size_t)b * CC + c0) * HW + p0;
#pragma unroll
    for (int i = 0; i < 4; i++) {
        int c = cl + 16 * i;
        float4 f = *(const float4*)(xb + (size_t)c * HW + p4 * 4);
        tile[c][p4 * 4 + 0] = f.x; tile[c][p4 * 4 + 1] = f.y;
        tile[c][p4 * 4 + 2] = f.z; tile[c][p4 * 4 + 3] = f.w;
    }
    __syncthreads();
    int c2 = t & 31, pl = t >> 5;
    unsigned short* xo = xt + ((size_t)b * HW + p0) * CC + c0;
#pragma unroll
    for (int i = 0; i < 8; i++) {
        int p = pl + 8 * i;
        float a = tile[2 * c2][p], bb = tile[2 * c2 + 1][p];
        unsigned int pk = (unsigned int)f2bf(a) | ((unsigned int)f2bf(bb) << 16);
        *(unsigned int*)(xo + (size_t)p * CC + 2 * c2) = pk;
    }
}

// ---------------- K0b: weights fp32 -> bf16 + psum zero ----------------------
__global__ __launch_bounds__(256) void wcvt(const float* __restrict__ Wq,
                                            const float* __restrict__ Wk,
                                            const float* __restrict__ Wv,
                                            const float* __restrict__ Wa,
                                            const float* __restrict__ Wse,
                                            unsigned short* __restrict__ wb,
                                            float* __restrict__ psum)
{
    int t = threadIdx.x;
    if (blockIdx.y == 4) {
        if (blockIdx.x == 0 && t < 64) psum[t] = 0.f;
        int idx = blockIdx.x * 256 + t;
        if (idx < 1024) {
            float4 f = *(const float4*)(Wse + (size_t)idx * 4);
            uint2 pk;
            pk.x = (unsigned int)f2bf(f.x) | ((unsigned int)f2bf(f.y) << 16);
            pk.y = (unsigned int)f2bf(f.z) | ((unsigned int)f2bf(f.w) << 16);
            *(uint2*)(wb + (size_t)4 * 65536 + (size_t)idx * 4) = pk;
        }
        return;
    }
    const float* srcs[4] = {Wq, Wk, Wv, Wa};
    const float* s = srcs[blockIdx.y];
    int idx = blockIdx.x * 256 + t;
    float4 f = *(const float4*)(s + (size_t)idx * 4);
    uint2 pk;
    pk.x = (unsigned int)f2bf(f.x) | ((unsigned int)f2bf(f.y) << 16);
    pk.y = (unsigned int)f2bf(f.z) | ((unsigned int)f2bf(f.w) << 16);
    *(uint2*)(wb + (size_t)blockIdx.y * 65536 + (size_t)idx * 4) = pk;
}

// ---------------- K1: qkv via MFMA bf16, outputs bf16 [(b*HW+p)][o] ----------
__global__ __launch_bounds__(256) void qkv_mfma(
    const unsigned short* __restrict__ xt, const unsigned short* __restrict__ wqkv,
    unsigned short* __restrict__ q_ws, unsigned short* __restrict__ k_ws,
    unsigned short* __restrict__ v_ws)
{
    int wsel = blockIdx.z;
    unsigned short* outp = (wsel == 0) ? q_ws : ((wsel == 1) ? k_ws : v_ws);
    int gp0 = blockIdx.x * 128, o0 = blockIdx.y * 128;

    __shared__ unsigned short As[128 * ASTR];
    __shared__ unsigned short Bs[128 * ASTR];
    const unsigned short* xb = xt + (size_t)gp0 * CC;
    const unsigned short* wbp = wqkv + (size_t)wsel * 65536 + (size_t)o0 * CC;

    int t = threadIdx.x;
    int wave = t >> 6, lane = t & 63;
    int mo = (wave & 1) * 64, no = (wave >> 1) * 64;
    int lm = lane & 15, lq = lane >> 4;
    int sr = t >> 3, sc = t & 7;

    f32x4 acc[4][4];
#pragma unroll
    for (int i = 0; i < 4; i++)
#pragma unroll
        for (int j = 0; j < 4; j++) acc[i][j] = (f32x4){0.f, 0.f, 0.f, 0.f};

    for (int k0 = 0; k0 < 256; k0 += 64) {
#pragma unroll
        for (int i = 0; i < 4; i++) {
            int r = sr + 32 * i;
            *(uint4*)&As[r * ASTR + sc * 8] = *(const uint4*)(xb + (size_t)r * CC + k0 + sc * 8);
            *(uint4*)&Bs[r * ASTR + sc * 8] = *(const uint4*)(wbp + (size_t)r * CC + k0 + sc * 8);
        }
        __syncthreads();
#pragma unroll
        for (int ks = 0; ks < 64; ks += 32) {
            bf16x8 af[4], bfr[4];
#pragma unroll
            for (int i = 0; i < 4; i++)
                af[i] = *(bf16x8*)&As[(mo + 16 * i + lm) * ASTR + ks + lq * 8];
#pragma unroll
            for (int j = 0; j < 4; j++)
                bfr[j] = *(bf16x8*)&Bs[(no + 16 * j + lm) * ASTR + ks + lq * 8];
#pragma unroll
            for (int i = 0; i < 4; i++)
#pragma unroll
                for (int j = 0; j < 4; j++)
                    acc[i][j] = __builtin_amdgcn_mfma_f32_16x16x32_bf16(
                        af[i], bfr[j], acc[i][j], 0, 0, 0);
        }
        __syncthreads();
    }
    unsigned short* ob = outp + (size_t)gp0 * CC + o0;
    bool ev = (lm & 1) == 0;
    int elm = lm & ~1;
#pragma unroll
    for (int i = 0; i < 4; i++)
#pragma unroll
        for (int j = 0; j < 4; j++)
#pragma unroll
            for (int r = 0; r < 4; r++) {
                float v = acc[i][j][r];
                float p = __shfl_xor(v, 1, 64);
                unsigned int pk = ev
                    ? ((unsigned int)f2bf(v) | ((unsigned int)f2bf(p) << 16))
                    : ((unsigned int)f2bf(p) | ((unsigned int)f2bf(v) << 16));
                if (ev == (r < 2)) {
                    int m = mo + 16 * i + lq * 4 + r;
                    int n = no + 16 * j + elm;
                    *(unsigned int*)(ob + (size_t)m * CC + n) = pk;
                }
            }
}

// ---------------- K3: agg via MFMA bf16 (ao bf16 in); BN1+ReLU / BN2 fused ---
__global__ __launch_bounds__(256) void agg_mfma(
    const unsigned short* __restrict__ ao, const unsigned short* __restrict__ wagg,
    const float* __restrict__ g1, const float* __restrict__ b1,
    const float* __restrict__ m1, const float* __restrict__ v1,
    const float* __restrict__ g2, const float* __restrict__ b2,
    const float* __restrict__ m2, const float* __restrict__ v2,
    float* __restrict__ y2)
{
    int gp0 = blockIdx.x * 128, o0 = blockIdx.y * 128;

    __shared__ unsigned short As[128 * ASTR];
    __shared__ unsigned short Bs[128 * ASTR];
    __shared__ float s1[256], o1[256], s2[256], o2[256];

    int t = threadIdx.x;
    {
        float sc1 = g1[t] * rsqrtf(v1[t] + 1e-5f);
        s1[t] = sc1; o1[t] = b1[t] - m1[t] * sc1;
        float sc2 = g2[t] * rsqrtf(v2[t] + 1e-5f);
        s2[t] = sc2; o2[t] = b2[t] - m2[t] * sc2;
    }

    const unsigned short* aob = ao + (size_t)gp0 * CC;
    const unsigned short* wbp = wagg + (size_t)o0 * CC;

    int wave = t >> 6, lane = t & 63;
    int mo = (wave & 1) * 64, no = (wave >> 1) * 64;
    int lm = lane & 15, lq = lane >> 4;
    int sr = t >> 3, sc = t & 7;

    f32x4 acc[4][4];
#pragma unroll
    for (int i = 0; i < 4; i++)
#pragma unroll
        for (int j = 0; j < 4; j++) acc[i][j] = (f32x4){0.f, 0.f, 0.f, 0.f};

    __syncthreads();

    for (int k0 = 0; k0 < 256; k0 += 64) {
#pragma unroll
        for (int i = 0; i < 4; i++) {
            int r = sr + 32 * i;
            int cb = k0 + sc * 8;
            uint4 u = *(const uint4*)(aob + (size_t)r * CC + cb);
            float e[8] = {bflo(u.x), bfhi(u.x), bflo(u.y), bfhi(u.y),
                          bflo(u.z), bfhi(u.z), bflo(u.w), bfhi(u.w)};
            unsigned short pk[8];
#pragma unroll
            for (int uu = 0; uu < 8; uu++) {
                float vv = fmaxf(e[uu] * s1[cb + uu] + o1[cb + uu], 0.f);
                pk[uu] = f2bf(vv);
            }
            *(uint4*)&As[r * ASTR + sc * 8] = *(uint4*)pk;
            *(uint4*)&Bs[r * ASTR + sc * 8] = *(const uint4*)(wbp + (size_t)r * CC + k0 + sc * 8);
        }
        __syncthreads();
#pragma unroll
        for (int ks = 0; ks < 64; ks += 32) {
            bf16x8 af[4], bfr[4];
#pragma unroll
            for (int i = 0; i < 4; i++)
                af[i] = *(bf16x8*)&As[(mo + 16 * i + lm) * ASTR + ks + lq * 8];
#pragma unroll
            for (int j = 0; j < 4; j++)
                bfr[j] = *(bf16x8*)&Bs[(no + 16 * j + lm) * ASTR + ks + lq * 8];
#pragma unroll
            for (int i = 0; i < 4; i++)
#pragma unroll
                for (int j = 0; j < 4; j++)
                    acc[i][j] = __builtin_amdgcn_mfma_f32_16x16x32_bf16(
                        af[i], bfr[j], acc[i][j], 0, 0, 0);
        }
        __syncthreads();
    }
    float* yb = y2 + (size_t)gp0 * CC + o0;
#pragma unroll
    for (int i = 0; i < 4; i++)
#pragma unroll
        for (int j = 0; j < 4; j++)
#pragma unroll
            for (int r = 0; r < 4; r++) {
                int m = mo + 16 * i + lq * 4 + r;
                int n = no + 16 * j + lm;
                yb[(size_t)m * CC + n] = acc[i][j][r] * s2[o0 + n] + o2[o0 + n];
            }
}

// ---------------- K2: local attention, bf16 LDS window, register softmax -----
__global__ __launch_bounds__(256, 4) void attn_kernel(
    const unsigned short* __restrict__ q_ws, const unsigned short* __restrict__ k_ws,
    const unsigned short* __restrict__ v_ws,
    const float* __restrict__ rel_h, const float* __restrict__ rel_w,
    unsigned short* __restrict__ ao_ws)
{
    __shared__ unsigned short kwin[WPX * KSTR2];   // 26112 B; holds k, then v
    __shared__ float relT[5 * RSTR];               // 2640 B

    int t = threadIdx.x;
    int tile = blockIdx.x;
    int n = blockIdx.y;
    int b = blockIdx.z;
    int tr = tile / 7, tc = tile - tr * 7;
    int h0 = tr * TH, w0 = tc * TW;
    const float* rel = (n == 0) ? rel_h : rel_w;
    const size_t base = (size_t)b * HW * CC + n * HD;

    {   // stage k window: raw bf16 uint4 copies (no conversion)
        int c8 = t & 15, pw0 = t >> 4;
#pragma unroll
        for (int it = 0; it < 6; it++) {
            int pw = pw0 + it * 16;
            int wr = pw / 12, wc = pw - wr * 12;
            int gh = h0 + wr - 2, gw = w0 + wc - 2;
            uint4 u = make_uint4(0u, 0u, 0u, 0u);
            if (gh >= 0 && gh < HH && gw >= 0 && gw < WW)
                u = *(const uint4*)(k_ws + base + (size_t)(gh * WW + gw) * CC + c8 * 8);
            *(uint4*)&kwin[pw * KSTR2 + c8 * 8] = u;
        }
        if (t < 128) {
#pragma unroll
            for (int tt = 0; tt < 5; tt++)
                relT[tt * RSTR + t] = rel[t * 5 + tt];
        }
    }
    __syncthreads();

    int px = t >> 3, c4g = t & 7;
    int pr = px >> 3, pc = px & 7;
    int ghp = h0 + pr, gwp = w0 + pc;
    const size_t pbase = base + (size_t)(ghp * WW + gwp) * CC;

    float4 q4[4];
#pragma unroll
    for (int i = 0; i < 4; i++) {
        uint2 uq = *(const uint2*)(q_ws + pbase + (c4g + 8 * i) * 4);
        q4[i] = make_float4(bflo(uq.x), bfhi(uq.x), bflo(uq.y), bfhi(uq.y));
    }

    float acc[30];
#pragma unroll
    for (int tt = 0; tt < 30; tt++) acc[tt] = 0.f;
#pragma unroll
    for (int i = 0; i < 4; i++) {
        float4 q = q4[i];
        int co = (c4g + 8 * i) * 4;       // channel offset (shorts)
#pragma unroll
        for (int tt = 0; tt < 25; tt++) {
            int di = tt / 5, dj = tt - 5 * (tt / 5);
            int wpx = (pr + di) * WC + pc + dj;
            uint2 ku = *(const uint2*)&kwin[wpx * KSTR2 + co];
            acc[tt] += q.x * bflo(ku.x) + q.y * bfhi(ku.x)
                     + q.z * bflo(ku.y) + q.w * bfhi(ku.y);
        }
#pragma unroll
        for (int tt = 0; tt < 5; tt++) {
            float4 r4 = *(const float4*)&relT[tt * RSTR + co];
            acc[25 + tt] += q.x * r4.x + q.y * r4.y + q.z * r4.z + q.w * r4.w;
        }
    }
#pragma unroll
    for (int tt = 0; tt < 30; tt++) {
#pragma unroll
        for (int m = 1; m < 8; m <<= 1)
            acc[tt] += __shfl_xor(acc[tt], m, 64);
    }
    // register softmax (all 8 lanes of a pixel hold identical sums)
    {
        const float inv = 0.08838834764831845f;
        float mx = -1e30f;
#pragma unroll
        for (int tt = 0; tt < 25; tt++) {
            int di = tt / 5, dj = tt - 5 * (tt / 5);
            acc[tt] = (acc[tt] + ((n == 0) ? acc[25 + di] : acc[25 + dj])) * inv;
            mx = fmaxf(mx, acc[tt]);
        }
        float sum = 0.f;
#pragma unroll
        for (int tt = 0; tt < 25; tt++) { acc[tt] = __expf(acc[tt] - mx); sum += acc[tt]; }
        float rs = 1.f / sum;
#pragma unroll
        for (int tt = 0; tt < 25; tt++) acc[tt] *= rs;
    }
    __syncthreads();   // all k reads done

    {   // stage v into same buffer (raw bf16 copies)
        int c8 = t & 15, pw0 = t >> 4;
#pragma unroll
        for (int it = 0; it < 6; it++) {
            int pw = pw0 + it * 16;
            int wr = pw / 12, wc = pw - wr * 12;
            int gh = h0 + wr - 2, gw = w0 + wc - 2;
            uint4 u = make_uint4(0u, 0u, 0u, 0u);
            if (gh >= 0 && gh < HH && gw >= 0 && gw < WW)
                u = *(const uint4*)(v_ws + base + (size_t)(gh * WW + gw) * CC + c8 * 8);
            *(uint4*)&kwin[pw * KSTR2 + c8 * 8] = u;
        }
    }
    __syncthreads();

    float4 oacc[4];
#pragma unroll
    for (int i = 0; i < 4; i++) oacc[i] = make_float4(0.f, 0.f, 0.f, 0.f);
#pragma unroll
    for (int tt = 0; tt < 25; tt++) {
        int di = tt / 5, dj = tt - 5 * (tt / 5);
        int wpx = (pr + di) * WC + pc + dj;
        float a = acc[tt];
#pragma unroll
        for (int i = 0; i < 4; i++) {
            uint2 vu = *(const uint2*)&kwin[wpx * KSTR2 + (c4g + 8 * i) * 4];
            oacc[i].x += a * bflo(vu.x); oacc[i].y += a * bfhi(vu.x);
            oacc[i].z += a * bflo(vu.y); oacc[i].w += a * bfhi(vu.y);
        }
    }
#pragma unroll
    for (int i = 0; i < 4; i++) {
        uint2 pk;
        pk.x = (unsigned int)f2bf(oacc[i].x) | ((unsigned int)f2bf(oacc[i].y) << 16);
        pk.y = (unsigned int)f2bf(oacc[i].z) | ((unsigned int)f2bf(oacc[i].w) << 16);
        *(uint2*)(ao_ws + pbase + (c4g + 8 * i) * 4) = pk;
    }
}

// ---------------- K4: SE squeeze via MFMA + fused channel-mean ---------------
__global__ __launch_bounds__(256) void se_in_mfma(
    const float* __restrict__ y2, const unsigned short* __restrict__ wse,
    const float* __restrict__ gin, const float* __restrict__ bin,
    const float* __restrict__ min_, const float* __restrict__ vin,
    float* __restrict__ s_ws, float* __restrict__ psum)
{
    int wave = threadIdx.x >> 6, lane = threadIdx.x & 63;
    int tile = blockIdx.x * 4 + wave;      // 0..783
    int gp0 = tile * 16;
    int b = tile / 196;
    int lm = lane & 15, lq = lane >> 4;

    f32x4 acc = (f32x4){0.f, 0.f, 0.f, 0.f};
    const float* ya = y2 + (size_t)(gp0 + lm) * CC;
#pragma unroll
    for (int k0 = 0; k0 < 256; k0 += 32) {
        int kb = k0 + lq * 8;
        float4 f0 = *(const float4*)(ya + kb);
        float4 f1 = *(const float4*)(ya + kb + 4);
        unsigned short pk[8] = {f2bf(f0.x), f2bf(f0.y), f2bf(f0.z), f2bf(f0.w),
                                f2bf(f1.x), f2bf(f1.y), f2bf(f1.z), f2bf(f1.w)};
        bf16x8 af = *(bf16x8*)pk;
        bf16x8 bf = *(const bf16x8*)(wse + (size_t)lm * CC + kb);
        acc = __builtin_amdgcn_mfma_f32_16x16x32_bf16(af, bf, acc, 0, 0, 0);
    }
    float sc = gin[lm] * rsqrtf(vin[lm] + 1e-5f);
    float off = bin[lm] - min_[lm] * sc;
    float sum4 = 0.f;
#pragma unroll
    for (int r = 0; r < 4; r++) {
        int row = lq * 4 + r;
        float v = fmaxf(acc[r] * sc + off, 0.f);
        s_ws[(size_t)(gp0 + row) * 16 + lm] = v;
        sum4 += v;
    }
    sum4 += __shfl_xor(sum4, 16, 64);
    sum4 += __shfl_xor(sum4, 32, 64);
    if (lane < 16) atomicAdd(&psum[b * 16 + lane], sum4);
}

// ---------------- K5: SE gate + excite conv + BN + fp32 store (NCHW) ---------
__global__ __launch_bounds__(256) void se_out_kernel(
    const float* __restrict__ s_ws, const float* __restrict__ psum,
    const float* __restrict__ fc1, const float* __restrict__ fc2,
    const float* __restrict__ se_Wout,
    const float* __restrict__ gout, const float* __restrict__ bout,
    const float* __restrict__ mout, const float* __restrict__ vout,
    float* __restrict__ out)
{
    int b = blockIdx.y;
    int px0 = blockIdx.x * 32;
    __shared__ float sl[32 * 17];
    __shared__ float wg[256 * 20];
    __shared__ float bo[256];
    __shared__ float gg[16];
    int t = threadIdx.x;

    if (t < 16) {
        float h = 0.f;
#pragma unroll
        for (int jj = 0; jj < 16; jj++)
            h += (psum[b * 16 + jj] * (1.f / 3136.f)) * fc1[jj];
        h = fmaxf(h, 0.f);
        float z = h * fc2[t];
        gg[t] = 1.f / (1.f + __expf(-z));
    }
    {
        const float* sb = s_ws + (size_t)(b * HW + px0) * 16;
#pragma unroll
        for (int i = 0; i < 2; i++) {
            int idx = t + 256 * i;
            sl[(idx >> 4) * 17 + (idx & 15)] = sb[idx];
        }
    }
    __syncthreads();
    {
        float sc = gout[t] * rsqrtf(vout[t] + 1e-5f);
        bo[t] = bout[t] - mout[t] * sc;
        const float* wr = se_Wout + (size_t)t * 16;
#pragma unroll
        for (int k = 0; k < 16; k++)
            wg[t * 20 + k] = wr[k] * gg[k] * sc;
    }
    __syncthreads();

    int px = t & 31, og = t >> 5;
    float4 s0 = *(float4*)&sl[px * 17 + 0];
    float4 s1v = *(float4*)&sl[px * 17 + 4];
    float4 s2v = *(float4*)&sl[px * 17 + 8];
    float4 s3 = *(float4*)&sl[px * 17 + 12];
    float* ob = out + (size_t)b * CC * HW + px0 + px;
#pragma unroll
    for (int oi = 0; oi < 32; oi++) {
        int o = og * 32 + oi;
        float4 w0 = *(float4*)&wg[o * 20 + 0];
        float4 w1 = *(float4*)&wg[o * 20 + 4];
        float4 w2 = *(float4*)&wg[o * 20 + 8];
        float4 w3 = *(float4*)&wg[o * 20 + 12];
        float r = bo[o]
            + s0.x * w0.x + s0.y * w0.y + s0.z * w0.z + s0.w * w0.w
            + s1v.x * w1.x + s1v.y * w1.y + s1v.z * w1.z + s1v.w * w1.w
            + s2v.x * w2.x + s2v.y * w2.y + s2v.z * w2.z + s2v.w * w2.w
            + s3.x * w3.x + s3.y * w3.y + s3.z * w3.z + s3.w * w3.w;
        ob[(size_t)o * HW] = r;
    }
}

extern "C" void kernel_launch(void* const* d_in, const int* in_sizes, int n_in,
                              void* d_out, int out_size, void* d_ws, size_t ws_size,
                              hipStream_t stream) {
    const float* x     = (const float*)d_in[0];
    const float* Wq    = (const float*)d_in[1];
    const float* Wk    = (const float*)d_in[2];
    const float* Wv    = (const float*)d_in[3];
    const float* rel_h = (const float*)d_in[4];
    const float* rel_w = (const float*)d_in[5];
    const float* agg_g1 = (const float*)d_in[6];
    const float* agg_b1 = (const float*)d_in[7];
    const float* agg_m1 = (const float*)d_in[8];
    const float* agg_v1 = (const float*)d_in[9];
    const float* agg_W  = (const float*)d_in[10];
    const float* agg_g2 = (const float*)d_in[11];
    const float* agg_b2 = (const float*)d_in[12];
    const float* agg_m2 = (const float*)d_in[13];
    const float* agg_v2 = (const float*)d_in[14];
    const float* se_Win = (const float*)d_in[15];
    const float* se_g_in = (const float*)d_in[16];
    const float* se_b_in = (const float*)d_in[17];
    const float* se_m_in = (const float*)d_in[18];
    const float* se_v_in = (const float*)d_in[19];
    const float* se_fc1  = (const float*)d_in[20];
    const float* se_fc2  = (const float*)d_in[21];
    const float* se_Wout = (const float*)d_in[22];
    const float* se_g_out = (const float*)d_in[23];
    const float* se_b_out = (const float*)d_in[24];
    const float* se_m_out = (const float*)d_in[25];
    const float* se_v_out = (const float*)d_in[26];

    const size_t NQ = (size_t)BB * HW * CC;   // 3,211,264
    unsigned short* q_ws  = (unsigned short*)d_ws;   // bf16, NQ each
    unsigned short* k_ws  = q_ws + NQ;
    unsigned short* v_ws  = k_ws + NQ;
    unsigned short* ao_ws = v_ws + NQ;
    unsigned short* xt    = ao_ws;                   // alias: xt dead before ao born
    float* y2_ws = (float*)d_ws;                     // alias over q+k (4*NQ bytes)
    float* s_ws  = (float*)(ao_ws + NQ);
    float* psum  = s_ws + (size_t)BB * HW * 16;
    unsigned short* wbf = (unsigned short*)(psum + 64);  // 4x65536 + 4096 bf16

    xt_cvt<<<dim3(49, 4, 4), 256, 0, stream>>>(x, xt);
    wcvt<<<dim3(64, 5), 256, 0, stream>>>(Wq, Wk, Wv, agg_W, se_Win, wbf, psum);
    qkv_mfma<<<dim3(98, 2, 3), 256, 0, stream>>>(xt, wbf, q_ws, k_ws, v_ws);
    attn_kernel<<<dim3(98, 2, 4), 256, 0, stream>>>(q_ws, k_ws, v_ws, rel_h, rel_w, ao_ws);
    agg_mfma<<<dim3(98, 2), 256, 0, stream>>>(ao_ws, wbf + 3 * 65536,
        agg_g1, agg_b1, agg_m1, agg_v1, agg_g2, agg_b2, agg_m2, agg_v2, y2_ws);
    se_in_mfma<<<dim3(196), 256, 0, stream>>>(y2_ws, wbf + 4 * 65536,
        se_g_in, se_b_in, se_m_in, se_v_in, s_ws, psum);
    se_out_kernel<<<dim3(98, 4), 256, 0, stream>>>(s_ws, psum, se_fc1, se_fc2,
        se_Wout, se_g_out, se_b_out, se_m_out, se_v_out, (float*)d_out);
}

// Round 10
// 211.054 us; speedup vs baseline: 1.6181x; 1.6181x over previous
//
#include <hip/hip_runtime.h>
#include <hip/hip_bf16.h>

#define HW 3136
#define HH 56
#define WW 56
#define BB 4
#define CC 256
#define HD 128

// attention tile geometry
#define TH 4
#define TW 8
#define WR 8    // TH+4
#define WC 12   // TW+4
#define WPX 96  // WR*WC
#define KSTR2 136   // shorts per window pixel in LDS (128 + 8 pad, 16B-aligned)
#define RSTR 132    // floats per rel row

// MFMA GEMM geometry: 128x128 tile, BK=64, LDS row = 64 bf16 + pad -> 72 (144 B)
#define ASTR 72

typedef __attribute__((ext_vector_type(8))) short bf16x8;
typedef __attribute__((ext_vector_type(4))) float f32x4;

__device__ __forceinline__ unsigned short f2bf(float f) {
    unsigned int u; __builtin_memcpy(&u, &f, 4);
    unsigned int r = u + 0x7FFFu + ((u >> 16) & 1u);   // RNE
    return (unsigned short)(r >> 16);
}
__device__ __forceinline__ float bflo(unsigned int u) {
    unsigned int x = u << 16; float f; __builtin_memcpy(&f, &x, 4); return f;
}
__device__ __forceinline__ float bfhi(unsigned int u) {
    unsigned int x = u & 0xFFFF0000u; float f; __builtin_memcpy(&f, &x, 4); return f;
}

// ---------------- K0a: x [b][c][p] fp32 -> xt [(b*HW+p)][c] bf16 -------------
__global__ __launch_bounds__(256) void xt_cvt(const float* __restrict__ x,
                                              unsigned short* __restrict__ xt)
{
    int b = blockIdx.z;
    int c0 = blockIdx.y * 64;
    int p0 = blockIdx.x * 64;
    __shared__ float tile[64][65];   // [channel][pixel]
    int t = threadIdx.x;
    int p4 = t & 15, cl = t >> 4;
    const float* xb = x + ((size_t)b * CC + c0) * HW + p0;
#pragma unroll
    for (int i = 0; i < 4; i++) {
        int c = cl + 16 * i;
        float4 f = *(const float4*)(xb + (size_t)c * HW + p4 * 4);
        tile[c][p4 * 4 + 0] = f.x; tile[c][p4 * 4 + 1] = f.y;
        tile[c][p4 * 4 + 2] = f.z; tile[c][p4 * 4 + 3] = f.w;
    }
    __syncthreads();
    int c2 = t & 31, pl = t >> 5;
    unsigned short* xo = xt + ((size_t)b * HW + p0) * CC + c0;
#pragma unroll
    for (int i = 0; i < 8; i++) {
        int p = pl + 8 * i;
        float a = tile[2 * c2][p], bb = tile[2 * c2 + 1][p];
        unsigned int pk = (unsigned int)f2bf(a) | ((unsigned int)f2bf(bb) << 16);
        *(unsigned int*)(xo + (size_t)p * CC + 2 * c2) = pk;
    }
}

// ---------------- K0b: weights fp32 -> bf16 + psum zero ----------------------
__global__ __launch_bounds__(256) void wcvt(const float* __restrict__ Wq,
                                            const float* __restrict__ Wk,
                                            const float* __restrict__ Wv,
                                            const float* __restrict__ Wa,
                                            const float* __restrict__ Wse,
                                            unsigned short* __restrict__ wb,
                                            float* __restrict__ psum)
{
    int t = threadIdx.x;
    if (blockIdx.y == 4) {
        if (blockIdx.x == 0 && t < 64) psum[t] = 0.f;
        int idx = blockIdx.x * 256 + t;
        if (idx < 1024) {
            float4 f = *(const float4*)(Wse + (size_t)idx * 4);
            uint2 pk;
            pk.x = (unsigned int)f2bf(f.x) | ((unsigned int)f2bf(f.y) << 16);
            pk.y = (unsigned int)f2bf(f.z) | ((unsigned int)f2bf(f.w) << 16);
            *(uint2*)(wb + (size_t)4 * 65536 + (size_t)idx * 4) = pk;
        }
        return;
    }
    const float* srcs[4] = {Wq, Wk, Wv, Wa};
    const float* s = srcs[blockIdx.y];
    int idx = blockIdx.x * 256 + t;
    float4 f = *(const float4*)(s + (size_t)idx * 4);
    uint2 pk;
    pk.x = (unsigned int)f2bf(f.x) | ((unsigned int)f2bf(f.y) << 16);
    pk.y = (unsigned int)f2bf(f.z) | ((unsigned int)f2bf(f.w) << 16);
    *(uint2*)(wb + (size_t)blockIdx.y * 65536 + (size_t)idx * 4) = pk;
}

// ---------------- K1: qkv via MFMA bf16, outputs bf16 [(b*HW+p)][o] ----------
__global__ __launch_bounds__(256) void qkv_mfma(
    const unsigned short* __restrict__ xt, const unsigned short* __restrict__ wqkv,
    unsigned short* __restrict__ q_ws, unsigned short* __restrict__ k_ws,
    unsigned short* __restrict__ v_ws)
{
    int wsel = blockIdx.z;
    unsigned short* outp = (wsel == 0) ? q_ws : ((wsel == 1) ? k_ws : v_ws);
    int gp0 = blockIdx.x * 128, o0 = blockIdx.y * 128;

    __shared__ unsigned short As[128 * ASTR];
    __shared__ unsigned short Bs[128 * ASTR];
    const unsigned short* xb = xt + (size_t)gp0 * CC;
    const unsigned short* wbp = wqkv + (size_t)wsel * 65536 + (size_t)o0 * CC;

    int t = threadIdx.x;
    int wave = t >> 6, lane = t & 63;
    int mo = (wave & 1) * 64, no = (wave >> 1) * 64;
    int lm = lane & 15, lq = lane >> 4;
    int sr = t >> 3, sc = t & 7;

    f32x4 acc[4][4];
#pragma unroll
    for (int i = 0; i < 4; i++)
#pragma unroll
        for (int j = 0; j < 4; j++) acc[i][j] = (f32x4){0.f, 0.f, 0.f, 0.f};

    for (int k0 = 0; k0 < 256; k0 += 64) {
#pragma unroll
        for (int i = 0; i < 4; i++) {
            int r = sr + 32 * i;
            *(uint4*)&As[r * ASTR + sc * 8] = *(const uint4*)(xb + (size_t)r * CC + k0 + sc * 8);
            *(uint4*)&Bs[r * ASTR + sc * 8] = *(const uint4*)(wbp + (size_t)r * CC + k0 + sc * 8);
        }
        __syncthreads();
#pragma unroll
        for (int ks = 0; ks < 64; ks += 32) {
            bf16x8 af[4], bfr[4];
#pragma unroll
            for (int i = 0; i < 4; i++)
                af[i] = *(bf16x8*)&As[(mo + 16 * i + lm) * ASTR + ks + lq * 8];
#pragma unroll
            for (int j = 0; j < 4; j++)
                bfr[j] = *(bf16x8*)&Bs[(no + 16 * j + lm) * ASTR + ks + lq * 8];
#pragma unroll
            for (int i = 0; i < 4; i++)
#pragma unroll
                for (int j = 0; j < 4; j++)
                    acc[i][j] = __builtin_amdgcn_mfma_f32_16x16x32_bf16(
                        af[i], bfr[j], acc[i][j], 0, 0, 0);
        }
        __syncthreads();
    }
    unsigned short* ob = outp + (size_t)gp0 * CC + o0;
    bool ev = (lm & 1) == 0;
    int elm = lm & ~1;
#pragma unroll
    for (int i = 0; i < 4; i++)
#pragma unroll
        for (int j = 0; j < 4; j++)
#pragma unroll
            for (int r = 0; r < 4; r++) {
                float v = acc[i][j][r];
                float p = __shfl_xor(v, 1, 64);
                unsigned int pk = ev
                    ? ((unsigned int)f2bf(v) | ((unsigned int)f2bf(p) << 16))
                    : ((unsigned int)f2bf(p) | ((unsigned int)f2bf(v) << 16));
                if (ev == (r < 2)) {
                    int m = mo + 16 * i + lq * 4 + r;
                    int n = no + 16 * j + elm;
                    *(unsigned int*)(ob + (size_t)m * CC + n) = pk;
                }
            }
}

// ---------------- K3: agg via MFMA bf16 (ao bf16 in); BN1+ReLU / BN2 fused ---
__global__ __launch_bounds__(256) void agg_mfma(
    const unsigned short* __restrict__ ao, const unsigned short* __restrict__ wagg,
    const float* __restrict__ g1, const float* __restrict__ b1,
    const float* __restrict__ m1, const float* __restrict__ v1,
    const float* __restrict__ g2, const float* __restrict__ b2,
    const float* __restrict__ m2, const float* __restrict__ v2,
    float* __restrict__ y2)
{
    int gp0 = blockIdx.x * 128, o0 = blockIdx.y * 128;

    __shared__ unsigned short As[128 * ASTR];
    __shared__ unsigned short Bs[128 * ASTR];
    __shared__ float s1[256], o1[256], s2[256], o2[256];

    int t = threadIdx.x;
    {
        float sc1 = g1[t] * rsqrtf(v1[t] + 1e-5f);
        s1[t] = sc1; o1[t] = b1[t] - m1[t] * sc1;
        float sc2 = g2[t] * rsqrtf(v2[t] + 1e-5f);
        s2[t] = sc2; o2[t] = b2[t] - m2[t] * sc2;
    }

    const unsigned short* aob = ao + (size_t)gp0 * CC;
    const unsigned short* wbp = wagg + (size_t)o0 * CC;

    int wave = t >> 6, lane = t & 63;
    int mo = (wave & 1) * 64, no = (wave >> 1) * 64;
    int lm = lane & 15, lq = lane >> 4;
    int sr = t >> 3, sc = t & 7;

    f32x4 acc[4][4];
#pragma unroll
    for (int i = 0; i < 4; i++)
#pragma unroll
        for (int j = 0; j < 4; j++) acc[i][j] = (f32x4){0.f, 0.f, 0.f, 0.f};

    __syncthreads();

    for (int k0 = 0; k0 < 256; k0 += 64) {
#pragma unroll
        for (int i = 0; i < 4; i++) {
            int r = sr + 32 * i;
            int cb = k0 + sc * 8;
            uint4 u = *(const uint4*)(aob + (size_t)r * CC + cb);
            float e[8] = {bflo(u.x), bfhi(u.x), bflo(u.y), bfhi(u.y),
                          bflo(u.z), bfhi(u.z), bflo(u.w), bfhi(u.w)};
            unsigned short pk[8];
#pragma unroll
            for (int uu = 0; uu < 8; uu++) {
                float vv = fmaxf(e[uu] * s1[cb + uu] + o1[cb + uu], 0.f);
                pk[uu] = f2bf(vv);
            }
            *(uint4*)&As[r * ASTR + sc * 8] = *(uint4*)pk;
            *(uint4*)&Bs[r * ASTR + sc * 8] = *(const uint4*)(wbp + (size_t)r * CC + k0 + sc * 8);
        }
        __syncthreads();
#pragma unroll
        for (int ks = 0; ks < 64; ks += 32) {
            bf16x8 af[4], bfr[4];
#pragma unroll
            for (int i = 0; i < 4; i++)
                af[i] = *(bf16x8*)&As[(mo + 16 * i + lm) * ASTR + ks + lq * 8];
#pragma unroll
            for (int j = 0; j < 4; j++)
                bfr[j] = *(bf16x8*)&Bs[(no + 16 * j + lm) * ASTR + ks + lq * 8];
#pragma unroll
            for (int i = 0; i < 4; i++)
#pragma unroll
                for (int j = 0; j < 4; j++)
                    acc[i][j] = __builtin_amdgcn_mfma_f32_16x16x32_bf16(
                        af[i], bfr[j], acc[i][j], 0, 0, 0);
        }
        __syncthreads();
    }
    float* yb = y2 + (size_t)gp0 * CC + o0;
#pragma unroll
    for (int i = 0; i < 4; i++)
#pragma unroll
        for (int j = 0; j < 4; j++)
#pragma unroll
            for (int r = 0; r < 4; r++) {
                int m = mo + 16 * i + lq * 4 + r;
                int n = no + 16 * j + lm;
                yb[(size_t)m * CC + n] = acc[i][j][r] * s2[o0 + n] + o2[o0 + n];
            }
}

// ---------------- K2: local attention, bf16 LDS window, register softmax -----
// NOTE: no min-waves clause — r9's (256,4) capped VGPR at 64 and spilled
// acc[30] to scratch (FETCH 18->180MB, WRITE 6->289MB). Let VGPR float (~112).
__global__ __launch_bounds__(256) void attn_kernel(
    const unsigned short* __restrict__ q_ws, const unsigned short* __restrict__ k_ws,
    const unsigned short* __restrict__ v_ws,
    const float* __restrict__ rel_h, const float* __restrict__ rel_w,
    unsigned short* __restrict__ ao_ws)
{
    __shared__ unsigned short kwin[WPX * KSTR2];   // 26112 B; holds k, then v
    __shared__ float relT[5 * RSTR];               // 2640 B

    int t = threadIdx.x;
    int tile = blockIdx.x;
    int n = blockIdx.y;
    int b = blockIdx.z;
    int tr = tile / 7, tc = tile - tr * 7;
    int h0 = tr * TH, w0 = tc * TW;
    const float* rel = (n == 0) ? rel_h : rel_w;
    const size_t base = (size_t)b * HW * CC + n * HD;

    {   // stage k window: raw bf16 uint4 copies (no conversion)
        int c8 = t & 15, pw0 = t >> 4;
#pragma unroll
        for (int it = 0; it < 6; it++) {
            int pw = pw0 + it * 16;
            int wr = pw / 12, wc = pw - wr * 12;
            int gh = h0 + wr - 2, gw = w0 + wc - 2;
            uint4 u = make_uint4(0u, 0u, 0u, 0u);
            if (gh >= 0 && gh < HH && gw >= 0 && gw < WW)
                u = *(const uint4*)(k_ws + base + (size_t)(gh * WW + gw) * CC + c8 * 8);
            *(uint4*)&kwin[pw * KSTR2 + c8 * 8] = u;
        }
        if (t < 128) {
#pragma unroll
            for (int tt = 0; tt < 5; tt++)
                relT[tt * RSTR + t] = rel[t * 5 + tt];
        }
    }
    __syncthreads();

    int px = t >> 3, c4g = t & 7;
    int pr = px >> 3, pc = px & 7;
    int ghp = h0 + pr, gwp = w0 + pc;
    const size_t pbase = base + (size_t)(ghp * WW + gwp) * CC;

    float4 q4[4];
#pragma unroll
    for (int i = 0; i < 4; i++) {
        uint2 uq = *(const uint2*)(q_ws + pbase + (c4g + 8 * i) * 4);
        q4[i] = make_float4(bflo(uq.x), bfhi(uq.x), bflo(uq.y), bfhi(uq.y));
    }

    float acc[30];
#pragma unroll
    for (int tt = 0; tt < 30; tt++) acc[tt] = 0.f;
#pragma unroll
    for (int i = 0; i < 4; i++) {
        float4 q = q4[i];
        int co = (c4g + 8 * i) * 4;       // channel offset (shorts)
#pragma unroll
        for (int tt = 0; tt < 25; tt++) {
            int di = tt / 5, dj = tt - 5 * (tt / 5);
            int wpx = (pr + di) * WC + pc + dj;
            uint2 ku = *(const uint2*)&kwin[wpx * KSTR2 + co];
            acc[tt] += q.x * bflo(ku.x) + q.y * bfhi(ku.x)
                     + q.z * bflo(ku.y) + q.w * bfhi(ku.y);
        }
#pragma unroll
        for (int tt = 0; tt < 5; tt++) {
            float4 r4 = *(const float4*)&relT[tt * RSTR + co];
            acc[25 + tt] += q.x * r4.x + q.y * r4.y + q.z * r4.z + q.w * r4.w;
        }
    }
#pragma unroll
    for (int tt = 0; tt < 30; tt++) {
#pragma unroll
        for (int m = 1; m < 8; m <<= 1)
            acc[tt] += __shfl_xor(acc[tt], m, 64);
    }
    // register softmax (all 8 lanes of a pixel hold identical sums)
    {
        const float inv = 0.08838834764831845f;
        float mx = -1e30f;
#pragma unroll
        for (int tt = 0; tt < 25; tt++) {
            int di = tt / 5, dj = tt - 5 * (tt / 5);
            acc[tt] = (acc[tt] + ((n == 0) ? acc[25 + di] : acc[25 + dj])) * inv;
            mx = fmaxf(mx, acc[tt]);
        }
        float sum = 0.f;
#pragma unroll
        for (int tt = 0; tt < 25; tt++) { acc[tt] = __expf(acc[tt] - mx); sum += acc[tt]; }
        float rs = 1.f / sum;
#pragma unroll
        for (int tt = 0; tt < 25; tt++) acc[tt] *= rs;
    }
    __syncthreads();   // all k reads done

    {   // stage v into same buffer (raw bf16 copies)
        int c8 = t & 15, pw0 = t >> 4;
#pragma unroll
        for (int it = 0; it < 6; it++) {
            int pw = pw0 + it * 16;
            int wr = pw / 12, wc = pw - wr * 12;
            int gh = h0 + wr - 2, gw = w0 + wc - 2;
            uint4 u = make_uint4(0u, 0u, 0u, 0u);
            if (gh >= 0 && gh < HH && gw >= 0 && gw < WW)
                u = *(const uint4*)(v_ws + base + (size_t)(gh * WW + gw) * CC + c8 * 8);
            *(uint4*)&kwin[pw * KSTR2 + c8 * 8] = u;
        }
    }
    __syncthreads();

    float4 oacc[4];
#pragma unroll
    for (int i = 0; i < 4; i++) oacc[i] = make_float4(0.f, 0.f, 0.f, 0.f);
#pragma unroll
    for (int tt = 0; tt < 25; tt++) {
        int di = tt / 5, dj = tt - 5 * (tt / 5);
        int wpx = (pr + di) * WC + pc + dj;
        float a = acc[tt];
#pragma unroll
        for (int i = 0; i < 4; i++) {
            uint2 vu = *(const uint2*)&kwin[wpx * KSTR2 + (c4g + 8 * i) * 4];
            oacc[i].x += a * bflo(vu.x); oacc[i].y += a * bfhi(vu.x);
            oacc[i].z += a * bflo(vu.y); oacc[i].w += a * bfhi(vu.y);
        }
    }
#pragma unroll
    for (int i = 0; i < 4; i++) {
        uint2 pk;
        pk.x = (unsigned int)f2bf(oacc[i].x) | ((unsigned int)f2bf(oacc[i].y) << 16);
        pk.y = (unsigned int)f2bf(oacc[i].z) | ((unsigned int)f2bf(oacc[i].w) << 16);
        *(uint2*)(ao_ws + pbase + (c4g + 8 * i) * 4) = pk;
    }
}

// ---------------- K4: SE squeeze via MFMA + fused channel-mean ---------------
__global__ __launch_bounds__(256) void se_in_mfma(
    const float* __restrict__ y2, const unsigned short* __restrict__ wse,
    const float* __restrict__ gin, const float* __restrict__ bin,
    const float* __restrict__ min_, const float* __restrict__ vin,
    float* __restrict__ s_ws, float* __restrict__ psum)
{
    int wave = threadIdx.x >> 6, lane = threadIdx.x & 63;
    int tile = blockIdx.x * 4 + wave;      // 0..783
    int gp0 = tile * 16;
    int b = tile / 196;
    int lm = lane & 15, lq = lane >> 4;

    f32x4 acc = (f32x4){0.f, 0.f, 0.f, 0.f};
    const float* ya = y2 + (size_t)(gp0 + lm) * CC;
#pragma unroll
    for (int k0 = 0; k0 < 256; k0 += 32) {
        int kb = k0 + lq * 8;
        float4 f0 = *(const float4*)(ya + kb);
        float4 f1 = *(const float4*)(ya + kb + 4);
        unsigned short pk[8] = {f2bf(f0.x), f2bf(f0.y), f2bf(f0.z), f2bf(f0.w),
                                f2bf(f1.x), f2bf(f1.y), f2bf(f1.z), f2bf(f1.w)};
        bf16x8 af = *(bf16x8*)pk;
        bf16x8 bf = *(const bf16x8*)(wse + (size_t)lm * CC + kb);
        acc = __builtin_amdgcn_mfma_f32_16x16x32_bf16(af, bf, acc, 0, 0, 0);
    }
    float sc = gin[lm] * rsqrtf(vin[lm] + 1e-5f);
    float off = bin[lm] - min_[lm] * sc;
    float sum4 = 0.f;
#pragma unroll
    for (int r = 0; r < 4; r++) {
        int row = lq * 4 + r;
        float v = fmaxf(acc[r] * sc + off, 0.f);
        s_ws[(size_t)(gp0 + row) * 16 + lm] = v;
        sum4 += v;
    }
    sum4 += __shfl_xor(sum4, 16, 64);
    sum4 += __shfl_xor(sum4, 32, 64);
    if (lane < 16) atomicAdd(&psum[b * 16 + lane], sum4);
}

// ---------------- K5: SE gate + excite conv + BN + fp32 store (NCHW) ---------
__global__ __launch_bounds__(256) void se_out_kernel(
    const float* __restrict__ s_ws, const float* __restrict__ psum,
    const float* __restrict__ fc1, const float* __restrict__ fc2,
    const float* __restrict__ se_Wout,
    const float* __restrict__ gout, const float* __restrict__ bout,
    const float* __restrict__ mout, const float* __restrict__ vout,
    float* __restrict__ out)
{
    int b = blockIdx.y;
    int px0 = blockIdx.x * 32;
    __shared__ float sl[32 * 17];
    __shared__ float wg[256 * 20];
    __shared__ float bo[256];
    __shared__ float gg[16];
    int t = threadIdx.x;

    if (t < 16) {
        float h = 0.f;
#pragma unroll
        for (int jj = 0; jj < 16; jj++)
            h += (psum[b * 16 + jj] * (1.f / 3136.f)) * fc1[jj];
        h = fmaxf(h, 0.f);
        float z = h * fc2[t];
        gg[t] = 1.f / (1.f + __expf(-z));
    }
    {
        const float* sb = s_ws + (size_t)(b * HW + px0) * 16;
#pragma unroll
        for (int i = 0; i < 2; i++) {
            int idx = t + 256 * i;
            sl[(idx >> 4) * 17 + (idx & 15)] = sb[idx];
        }
    }
    __syncthreads();
    {
        float sc = gout[t] * rsqrtf(vout[t] + 1e-5f);
        bo[t] = bout[t] - mout[t] * sc;
        const float* wr = se_Wout + (size_t)t * 16;
#pragma unroll
        for (int k = 0; k < 16; k++)
            wg[t * 20 + k] = wr[k] * gg[k] * sc;
    }
    __syncthreads();

    int px = t & 31, og = t >> 5;
    float4 s0 = *(float4*)&sl[px * 17 + 0];
    float4 s1v = *(float4*)&sl[px * 17 + 4];
    float4 s2v = *(float4*)&sl[px * 17 + 8];
    float4 s3 = *(float4*)&sl[px * 17 + 12];
    float* ob = out + (size_t)b * CC * HW + px0 + px;
#pragma unroll
    for (int oi = 0; oi < 32; oi++) {
        int o = og * 32 + oi;
        float4 w0 = *(float4*)&wg[o * 20 + 0];
        float4 w1 = *(float4*)&wg[o * 20 + 4];
        float4 w2 = *(float4*)&wg[o * 20 + 8];
        float4 w3 = *(float4*)&wg[o * 20 + 12];
        float r = bo[o]
            + s0.x * w0.x + s0.y * w0.y + s0.z * w0.z + s0.w * w0.w
            + s1v.x * w1.x + s1v.y * w1.y + s1v.z * w1.z + s1v.w * w1.w
            + s2v.x * w2.x + s2v.y * w2.y + s2v.z * w2.z + s2v.w * w2.w
            + s3.x * w3.x + s3.y * w3.y + s3.z * w3.z + s3.w * w3.w;
        ob[(size_t)o * HW] = r;
    }
}

extern "C" void kernel_launch(void* const* d_in, const int* in_sizes, int n_in,
                              void* d_out, int out_size, void* d_ws, size_t ws_size,
                              hipStream_t stream) {
    const float* x     = (const float*)d_in[0];
    const float* Wq    = (const float*)d_in[1];
    const float* Wk    = (const float*)d_in[2];
    const float* Wv    = (const float*)d_in[3];
    const float* rel_h = (const float*)d_in[4];
    const float* rel_w = (const float*)d_in[5];
    const float* agg_g1 = (const float*)d_in[6];
    const float* agg_b1 = (const float*)d_in[7];
    const float* agg_m1 = (const float*)d_in[8];
    const float* agg_v1 = (const float*)d_in[9];
    const float* agg_W  = (const float*)d_in[10];
    const float* agg_g2 = (const float*)d_in[11];
    const float* agg_b2 = (const float*)d_in[12];
    const float* agg_m2 = (const float*)d_in[13];
    const float* agg_v2 = (const float*)d_in[14];
    const float* se_Win = (const float*)d_in[15];
    const float* se_g_in = (const float*)d_in[16];
    const float* se_b_in = (const float*)d_in[17];
    const float* se_m_in = (const float*)d_in[18];
    const float* se_v_in = (const float*)d_in[19];
    const float* se_fc1  = (const float*)d_in[20];
    const float* se_fc2  = (const float*)d_in[21];
    const float* se_Wout = (const float*)d_in[22];
    const float* se_g_out = (const float*)d_in[23];
    const float* se_b_out = (const float*)d_in[24];
    const float* se_m_out = (const float*)d_in[25];
    const float* se_v_out = (const float*)d_in[26];

    const size_t NQ = (size_t)BB * HW * CC;   // 3,211,264
    unsigned short* q_ws  = (unsigned short*)d_ws;   // bf16, NQ each
    unsigned short* k_ws  = q_ws + NQ;
    unsigned short* v_ws  = k_ws + NQ;
    unsigned short* ao_ws = v_ws + NQ;
    unsigned short* xt    = ao_ws;                   // alias: xt dead before ao born
    float* y2_ws = (float*)d_ws;                     // alias over q+k (4*NQ bytes)
    float* s_ws  = (float*)(ao_ws + NQ);
    float* psum  = s_ws + (size_t)BB * HW * 16;
    unsigned short* wbf = (unsigned short*)(psum + 64);  // 4x65536 + 4096 bf16

    xt_cvt<<<dim3(49, 4, 4), 256, 0, stream>>>(x, xt);
    wcvt<<<dim3(64, 5), 256, 0, stream>>>(Wq, Wk, Wv, agg_W, se_Win, wbf, psum);
    qkv_mfma<<<dim3(98, 2, 3), 256, 0, stream>>>(xt, wbf, q_ws, k_ws, v_ws);
    attn_kernel<<<dim3(98, 2, 4), 256, 0, stream>>>(q_ws, k_ws, v_ws, rel_h, rel_w, ao_ws);
    agg_mfma<<<dim3(98, 2), 256, 0, stream>>>(ao_ws, wbf + 3 * 65536,
        agg_g1, agg_b1, agg_m1, agg_v1, agg_g2, agg_b2, agg_m2, agg_v2, y2_ws);
    se_in_mfma<<<dim3(196), 256, 0, stream>>>(y2_ws, wbf + 4 * 65536,
        se_g_in, se_b_in, se_m_in, se_v_in, s_ws, psum);
    se_out_kernel<<<dim3(98, 4), 256, 0, stream>>>(s_ws, psum, se_fc1, se_fc2,
        se_Wout, se_g_out, se_b_out, se_m_out, se_v_out, (float*)d_out);
}

// Round 11
// 199.593 us; speedup vs baseline: 1.7110x; 1.0574x over previous
//
#include <hip/hip_runtime.h>
#include <hip/hip_bf16.h>

#define HW 3136
#define HH 56
#define WW 56
#define BB 4
#define CC 256
#define HD 128

// attention tile geometry: 2x8 pixel tile, 16 lanes per pixel
#define TH 2
#define TW 8
#define WR 6    // TH+4
#define WC 12   // TW+4
#define WPX 72  // WR*WC
#define KSTR2 136   // shorts per window pixel in LDS (128 + 8 pad; 272B rows)
#define RSTR 132    // floats per rel row

// MFMA GEMM geometry: 128x128 tile, BK=64, LDS row = 64 bf16 + pad -> 72 (144 B)
#define ASTR 72

typedef __attribute__((ext_vector_type(8))) short bf16x8;
typedef __attribute__((ext_vector_type(4))) float f32x4;

__device__ __forceinline__ unsigned short f2bf(float f) {
    unsigned int u; __builtin_memcpy(&u, &f, 4);
    unsigned int r = u + 0x7FFFu + ((u >> 16) & 1u);   // RNE
    return (unsigned short)(r >> 16);
}
__device__ __forceinline__ float bflo(unsigned int u) {
    unsigned int x = u << 16; float f; __builtin_memcpy(&f, &x, 4); return f;
}
__device__ __forceinline__ float bfhi(unsigned int u) {
    unsigned int x = u & 0xFFFF0000u; float f; __builtin_memcpy(&f, &x, 4); return f;
}

// ---------------- K0a: x [b][c][p] fp32 -> xt [(b*HW+p)][c] bf16 -------------
__global__ __launch_bounds__(256) void xt_cvt(const float* __restrict__ x,
                                              unsigned short* __restrict__ xt)
{
    int b = blockIdx.z;
    int c0 = blockIdx.y * 64;
    int p0 = blockIdx.x * 64;
    __shared__ float tile[64][65];   // [channel][pixel]
    int t = threadIdx.x;
    int p4 = t & 15, cl = t >> 4;
    const float* xb = x + ((size_t)b * CC + c0) * HW + p0;
#pragma unroll
    for (int i = 0; i < 4; i++) {
        int c = cl + 16 * i;
        float4 f = *(const float4*)(xb + (size_t)c * HW + p4 * 4);
        tile[c][p4 * 4 + 0] = f.x; tile[c][p4 * 4 + 1] = f.y;
        tile[c][p4 * 4 + 2] = f.z; tile[c][p4 * 4 + 3] = f.w;
    }
    __syncthreads();
    int c2 = t & 31, pl = t >> 5;
    unsigned short* xo = xt + ((size_t)b * HW + p0) * CC + c0;
#pragma unroll
    for (int i = 0; i < 8; i++) {
        int p = pl + 8 * i;
        float a = tile[2 * c2][p], bb = tile[2 * c2 + 1][p];
        unsigned int pk = (unsigned int)f2bf(a) | ((unsigned int)f2bf(bb) << 16);
        *(unsigned int*)(xo + (size_t)p * CC + 2 * c2) = pk;
    }
}

// ---------------- K0b: weights fp32 -> bf16 + psum zero ----------------------
__global__ __launch_bounds__(256) void wcvt(const float* __restrict__ Wq,
                                            const float* __restrict__ Wk,
                                            const float* __restrict__ Wv,
                                            const float* __restrict__ Wa,
                                            const float* __restrict__ Wse,
                                            unsigned short* __restrict__ wb,
                                            float* __restrict__ psum)
{
    int t = threadIdx.x;
    if (blockIdx.y == 4) {
        if (blockIdx.x == 0 && t < 64) psum[t] = 0.f;
        int idx = blockIdx.x * 256 + t;
        if (idx < 1024) {
            float4 f = *(const float4*)(Wse + (size_t)idx * 4);
            uint2 pk;
            pk.x = (unsigned int)f2bf(f.x) | ((unsigned int)f2bf(f.y) << 16);
            pk.y = (unsigned int)f2bf(f.z) | ((unsigned int)f2bf(f.w) << 16);
            *(uint2*)(wb + (size_t)4 * 65536 + (size_t)idx * 4) = pk;
        }
        return;
    }
    const float* srcs[4] = {Wq, Wk, Wv, Wa};
    const float* s = srcs[blockIdx.y];
    int idx = blockIdx.x * 256 + t;
    float4 f = *(const float4*)(s + (size_t)idx * 4);
    uint2 pk;
    pk.x = (unsigned int)f2bf(f.x) | ((unsigned int)f2bf(f.y) << 16);
    pk.y = (unsigned int)f2bf(f.z) | ((unsigned int)f2bf(f.w) << 16);
    *(uint2*)(wb + (size_t)blockIdx.y * 65536 + (size_t)idx * 4) = pk;
}

// ---------------- K1: qkv via MFMA bf16, outputs bf16 [(b*HW+p)][o] ----------
__global__ __launch_bounds__(256) void qkv_mfma(
    const unsigned short* __restrict__ xt, const unsigned short* __restrict__ wqkv,
    unsigned short* __restrict__ q_ws, unsigned short* __restrict__ k_ws,
    unsigned short* __restrict__ v_ws)
{
    int wsel = blockIdx.z;
    unsigned short* outp = (wsel == 0) ? q_ws : ((wsel == 1) ? k_ws : v_ws);
    int gp0 = blockIdx.x * 128, o0 = blockIdx.y * 128;

    __shared__ unsigned short As[128 * ASTR];
    __shared__ unsigned short Bs[128 * ASTR];
    const unsigned short* xb = xt + (size_t)gp0 * CC;
    const unsigned short* wbp = wqkv + (size_t)wsel * 65536 + (size_t)o0 * CC;

    int t = threadIdx.x;
    int wave = t >> 6, lane = t & 63;
    int mo = (wave & 1) * 64, no = (wave >> 1) * 64;
    int lm = lane & 15, lq = lane >> 4;
    int sr = t >> 3, sc = t & 7;

    f32x4 acc[4][4];
#pragma unroll
    for (int i = 0; i < 4; i++)
#pragma unroll
        for (int j = 0; j < 4; j++) acc[i][j] = (f32x4){0.f, 0.f, 0.f, 0.f};

    for (int k0 = 0; k0 < 256; k0 += 64) {
#pragma unroll
        for (int i = 0; i < 4; i++) {
            int r = sr + 32 * i;
            *(uint4*)&As[r * ASTR + sc * 8] = *(const uint4*)(xb + (size_t)r * CC + k0 + sc * 8);
            *(uint4*)&Bs[r * ASTR + sc * 8] = *(const uint4*)(wbp + (size_t)r * CC + k0 + sc * 8);
        }
        __syncthreads();
#pragma unroll
        for (int ks = 0; ks < 64; ks += 32) {
            bf16x8 af[4], bfr[4];
#pragma unroll
            for (int i = 0; i < 4; i++)
                af[i] = *(bf16x8*)&As[(mo + 16 * i + lm) * ASTR + ks + lq * 8];
#pragma unroll
            for (int j = 0; j < 4; j++)
                bfr[j] = *(bf16x8*)&Bs[(no + 16 * j + lm) * ASTR + ks + lq * 8];
#pragma unroll
            for (int i = 0; i < 4; i++)
#pragma unroll
                for (int j = 0; j < 4; j++)
                    acc[i][j] = __builtin_amdgcn_mfma_f32_16x16x32_bf16(
                        af[i], bfr[j], acc[i][j], 0, 0, 0);
        }
        __syncthreads();
    }
    unsigned short* ob = outp + (size_t)gp0 * CC + o0;
    bool ev = (lm & 1) == 0;
    int elm = lm & ~1;
#pragma unroll
    for (int i = 0; i < 4; i++)
#pragma unroll
        for (int j = 0; j < 4; j++)
#pragma unroll
            for (int r = 0; r < 4; r++) {
                float v = acc[i][j][r];
                float p = __shfl_xor(v, 1, 64);
                unsigned int pk = ev
                    ? ((unsigned int)f2bf(v) | ((unsigned int)f2bf(p) << 16))
                    : ((unsigned int)f2bf(p) | ((unsigned int)f2bf(v) << 16));
                if (ev == (r < 2)) {
                    int m = mo + 16 * i + lq * 4 + r;
                    int n = no + 16 * j + elm;
                    *(unsigned int*)(ob + (size_t)m * CC + n) = pk;
                }
            }
}

// ---------------- K3: agg via MFMA bf16 (ao bf16 in); BN1+ReLU / BN2 fused ---
__global__ __launch_bounds__(256) void agg_mfma(
    const unsigned short* __restrict__ ao, const unsigned short* __restrict__ wagg,
    const float* __restrict__ g1, const float* __restrict__ b1,
    const float* __restrict__ m1, const float* __restrict__ v1,
    const float* __restrict__ g2, const float* __restrict__ b2,
    const float* __restrict__ m2, const float* __restrict__ v2,
    float* __restrict__ y2)
{
    int gp0 = blockIdx.x * 128, o0 = blockIdx.y * 128;

    __shared__ unsigned short As[128 * ASTR];
    __shared__ unsigned short Bs[128 * ASTR];
    __shared__ float s1[256], o1[256], s2[256], o2[256];

    int t = threadIdx.x;
    {
        float sc1 = g1[t] * rsqrtf(v1[t] + 1e-5f);
        s1[t] = sc1; o1[t] = b1[t] - m1[t] * sc1;
        float sc2 = g2[t] * rsqrtf(v2[t] + 1e-5f);
        s2[t] = sc2; o2[t] = b2[t] - m2[t] * sc2;
    }

    const unsigned short* aob = ao + (size_t)gp0 * CC;
    const unsigned short* wbp = wagg + (size_t)o0 * CC;

    int wave = t >> 6, lane = t & 63;
    int mo = (wave & 1) * 64, no = (wave >> 1) * 64;
    int lm = lane & 15, lq = lane >> 4;
    int sr = t >> 3, sc = t & 7;

    f32x4 acc[4][4];
#pragma unroll
    for (int i = 0; i < 4; i++)
#pragma unroll
        for (int j = 0; j < 4; j++) acc[i][j] = (f32x4){0.f, 0.f, 0.f, 0.f};

    __syncthreads();

    for (int k0 = 0; k0 < 256; k0 += 64) {
#pragma unroll
        for (int i = 0; i < 4; i++) {
            int r = sr + 32 * i;
            int cb = k0 + sc * 8;
            uint4 u = *(const uint4*)(aob + (size_t)r * CC + cb);
            float e[8] = {bflo(u.x), bfhi(u.x), bflo(u.y), bfhi(u.y),
                          bflo(u.z), bfhi(u.z), bflo(u.w), bfhi(u.w)};
            unsigned short pk[8];
#pragma unroll
            for (int uu = 0; uu < 8; uu++) {
                float vv = fmaxf(e[uu] * s1[cb + uu] + o1[cb + uu], 0.f);
                pk[uu] = f2bf(vv);
            }
            *(uint4*)&As[r * ASTR + sc * 8] = *(uint4*)pk;
            *(uint4*)&Bs[r * ASTR + sc * 8] = *(const uint4*)(wbp + (size_t)r * CC + k0 + sc * 8);
        }
        __syncthreads();
#pragma unroll
        for (int ks = 0; ks < 64; ks += 32) {
            bf16x8 af[4], bfr[4];
#pragma unroll
            for (int i = 0; i < 4; i++)
                af[i] = *(bf16x8*)&As[(mo + 16 * i + lm) * ASTR + ks + lq * 8];
#pragma unroll
            for (int j = 0; j < 4; j++)
                bfr[j] = *(bf16x8*)&Bs[(no + 16 * j + lm) * ASTR + ks + lq * 8];
#pragma unroll
            for (int i = 0; i < 4; i++)
#pragma unroll
                for (int j = 0; j < 4; j++)
                    acc[i][j] = __builtin_amdgcn_mfma_f32_16x16x32_bf16(
                        af[i], bfr[j], acc[i][j], 0, 0, 0);
        }
        __syncthreads();
    }
    float* yb = y2 + (size_t)gp0 * CC + o0;
#pragma unroll
    for (int i = 0; i < 4; i++)
#pragma unroll
        for (int j = 0; j < 4; j++)
#pragma unroll
            for (int r = 0; r < 4; r++) {
                int m = mo + 16 * i + lq * 4 + r;
                int n = no + 16 * j + lm;
                yb[(size_t)m * CC + n] = acc[i][j][r] * s2[o0 + n] + o2[o0 + n];
            }
}

// ---------------- K2: local attention, 16 lanes/pixel, 2x8 tile --------------
// r8-r10 lesson: kernel is wave-parallelism-bound (occ 9-17%). 16 lanes/px
// shrinks VGPR (~80) and 2x8 tiles double the grid -> ~6 blocks/CU.
__global__ __launch_bounds__(256) void attn_kernel(
    const unsigned short* __restrict__ q_ws, const unsigned short* __restrict__ k_ws,
    const unsigned short* __restrict__ v_ws,
    const float* __restrict__ rel_h, const float* __restrict__ rel_w,
    unsigned short* __restrict__ ao_ws)
{
    __shared__ unsigned short kwin[WPX * KSTR2];   // 19584 B; holds k, then v
    __shared__ float relT[5 * RSTR];               // 2640 B

    int t = threadIdx.x;
    int tile = blockIdx.x;                         // 0..195 (28 x 7)
    int n = blockIdx.y;
    int b = blockIdx.z;
    int tr = tile / 7, tc = tile - tr * 7;
    int h0 = tr * TH, w0 = tc * TW;
    const float* rel = (n == 0) ? rel_h : rel_w;
    const size_t base = (size_t)b * HW * CC + n * HD;

    {   // stage k window: 16 granule-threads x 16 px per pass, 5 passes
        int c16 = t & 15, pwt = t >> 4;
#pragma unroll
        for (int it = 0; it < 5; it++) {
            int pw = pwt + it * 16;
            if (pw < WPX) {
                int wr = pw / 12, wc = pw - wr * 12;
                int gh = h0 + wr - 2, gw = w0 + wc - 2;
                uint4 u = make_uint4(0u, 0u, 0u, 0u);
                if (gh >= 0 && gh < HH && gw >= 0 && gw < WW)
                    u = *(const uint4*)(k_ws + base + (size_t)(gh * WW + gw) * CC + c16 * 8);
                *(uint4*)&kwin[pw * KSTR2 + c16 * 8] = u;
            }
        }
        if (t < 128) {
#pragma unroll
            for (int tt = 0; tt < 5; tt++)
                relT[tt * RSTR + t] = rel[t * 5 + tt];
        }
    }
    __syncthreads();

    int px = t >> 4, cg = t & 15;      // 16 px, 16 lanes (8 ch) per px
    int pr = px >> 3, pc = px & 7;
    int ghp = h0 + pr, gwp = w0 + pc;
    const size_t pbase = base + (size_t)(ghp * WW + gwp) * CC;

    float q[8];
    {
        uint4 uq = *(const uint4*)(q_ws + pbase + cg * 8);
        q[0] = bflo(uq.x); q[1] = bfhi(uq.x); q[2] = bflo(uq.y); q[3] = bfhi(uq.y);
        q[4] = bflo(uq.z); q[5] = bfhi(uq.z); q[6] = bflo(uq.w); q[7] = bfhi(uq.w);
    }

    float acc[30];
#pragma unroll
    for (int tt = 0; tt < 25; tt++) {
        int di = tt / 5, dj = tt - 5 * (tt / 5);
        int wpx = (pr + di) * WC + pc + dj;
        uint4 ku = *(const uint4*)&kwin[wpx * KSTR2 + cg * 8];
        acc[tt] = q[0] * bflo(ku.x) + q[1] * bfhi(ku.x)
                + q[2] * bflo(ku.y) + q[3] * bfhi(ku.y)
                + q[4] * bflo(ku.z) + q[5] * bfhi(ku.z)
                + q[6] * bflo(ku.w) + q[7] * bfhi(ku.w);
    }
#pragma unroll
    for (int tt = 0; tt < 5; tt++) {
        float4 r0 = *(const float4*)&relT[tt * RSTR + cg * 8];
        float4 r1 = *(const float4*)&relT[tt * RSTR + cg * 8 + 4];
        acc[25 + tt] = q[0] * r0.x + q[1] * r0.y + q[2] * r0.z + q[3] * r0.w
                     + q[4] * r1.x + q[5] * r1.y + q[6] * r1.z + q[7] * r1.w;
    }
    // butterfly over the 16 lanes sharing a pixel
#pragma unroll
    for (int tt = 0; tt < 30; tt++) {
#pragma unroll
        for (int m = 1; m < 16; m <<= 1)
            acc[tt] += __shfl_xor(acc[tt], m, 64);
    }
    // register softmax (all 16 lanes hold identical sums)
    {
        const float inv = 0.08838834764831845f;  // 1/sqrt(128)
        float mx = -1e30f;
#pragma unroll
        for (int tt = 0; tt < 25; tt++) {
            int di = tt / 5, dj = tt - 5 * (tt / 5);
            acc[tt] = (acc[tt] + ((n == 0) ? acc[25 + di] : acc[25 + dj])) * inv;
            mx = fmaxf(mx, acc[tt]);
        }
        float sum = 0.f;
#pragma unroll
        for (int tt = 0; tt < 25; tt++) { acc[tt] = __expf(acc[tt] - mx); sum += acc[tt]; }
        float rs = 1.f / sum;
#pragma unroll
        for (int tt = 0; tt < 25; tt++) acc[tt] *= rs;
    }
    __syncthreads();   // all k reads done

    {   // stage v into same buffer
        int c16 = t & 15, pwt = t >> 4;
#pragma unroll
        for (int it = 0; it < 5; it++) {
            int pw = pwt + it * 16;
            if (pw < WPX) {
                int wr = pw / 12, wc = pw - wr * 12;
                int gh = h0 + wr - 2, gw = w0 + wc - 2;
                uint4 u = make_uint4(0u, 0u, 0u, 0u);
                if (gh >= 0 && gh < HH && gw >= 0 && gw < WW)
                    u = *(const uint4*)(v_ws + base + (size_t)(gh * WW + gw) * CC + c16 * 8);
                *(uint4*)&kwin[pw * KSTR2 + c16 * 8] = u;
            }
        }
    }
    __syncthreads();

    float o[8];
#pragma unroll
    for (int i = 0; i < 8; i++) o[i] = 0.f;
#pragma unroll
    for (int tt = 0; tt < 25; tt++) {
        int di = tt / 5, dj = tt - 5 * (tt / 5);
        int wpx = (pr + di) * WC + pc + dj;
        float a = acc[tt];
        uint4 vu = *(const uint4*)&kwin[wpx * KSTR2 + cg * 8];
        o[0] += a * bflo(vu.x); o[1] += a * bfhi(vu.x);
        o[2] += a * bflo(vu.y); o[3] += a * bfhi(vu.y);
        o[4] += a * bflo(vu.z); o[5] += a * bfhi(vu.z);
        o[6] += a * bflo(vu.w); o[7] += a * bfhi(vu.w);
    }
    uint4 pk;
    pk.x = (unsigned int)f2bf(o[0]) | ((unsigned int)f2bf(o[1]) << 16);
    pk.y = (unsigned int)f2bf(o[2]) | ((unsigned int)f2bf(o[3]) << 16);
    pk.z = (unsigned int)f2bf(o[4]) | ((unsigned int)f2bf(o[5]) << 16);
    pk.w = (unsigned int)f2bf(o[6]) | ((unsigned int)f2bf(o[7]) << 16);
    *(uint4*)(ao_ws + pbase + cg * 8) = pk;
}

// ---------------- K4: SE squeeze via MFMA + fused channel-mean ---------------
__global__ __launch_bounds__(256) void se_in_mfma(
    const float* __restrict__ y2, const unsigned short* __restrict__ wse,
    const float* __restrict__ gin, const float* __restrict__ bin,
    const float* __restrict__ min_, const float* __restrict__ vin,
    float* __restrict__ s_ws, float* __restrict__ psum)
{
    int wave = threadIdx.x >> 6, lane = threadIdx.x & 63;
    int tile = blockIdx.x * 4 + wave;      // 0..783
    int gp0 = tile * 16;
    int b = tile / 196;
    int lm = lane & 15, lq = lane >> 4;

    f32x4 acc = (f32x4){0.f, 0.f, 0.f, 0.f};
    const float* ya = y2 + (size_t)(gp0 + lm) * CC;
#pragma unroll
    for (int k0 = 0; k0 < 256; k0 += 32) {
        int kb = k0 + lq * 8;
        float4 f0 = *(const float4*)(ya + kb);
        float4 f1 = *(const float4*)(ya + kb + 4);
        unsigned short pk[8] = {f2bf(f0.x), f2bf(f0.y), f2bf(f0.z), f2bf(f0.w),
                                f2bf(f1.x), f2bf(f1.y), f2bf(f1.z), f2bf(f1.w)};
        bf16x8 af = *(bf16x8*)pk;
        bf16x8 bf = *(const bf16x8*)(wse + (size_t)lm * CC + kb);
        acc = __builtin_amdgcn_mfma_f32_16x16x32_bf16(af, bf, acc, 0, 0, 0);
    }
    float sc = gin[lm] * rsqrtf(vin[lm] + 1e-5f);
    float off = bin[lm] - min_[lm] * sc;
    float sum4 = 0.f;
#pragma unroll
    for (int r = 0; r < 4; r++) {
        int row = lq * 4 + r;
        float v = fmaxf(acc[r] * sc + off, 0.f);
        s_ws[(size_t)(gp0 + row) * 16 + lm] = v;
        sum4 += v;
    }
    sum4 += __shfl_xor(sum4, 16, 64);
    sum4 += __shfl_xor(sum4, 32, 64);
    if (lane < 16) atomicAdd(&psum[b * 16 + lane], sum4);
}

// ---------------- K5: SE gate + excite conv + BN + fp32 store (NCHW) ---------
__global__ __launch_bounds__(256) void se_out_kernel(
    const float* __restrict__ s_ws, const float* __restrict__ psum,
    const float* __restrict__ fc1, const float* __restrict__ fc2,
    const float* __restrict__ se_Wout,
    const float* __restrict__ gout, const float* __restrict__ bout,
    const float* __restrict__ mout, const float* __restrict__ vout,
    float* __restrict__ out)
{
    int b = blockIdx.y;
    int px0 = blockIdx.x * 32;
    __shared__ float sl[32 * 17];
    __shared__ float wg[256 * 20];
    __shared__ float bo[256];
    __shared__ float gg[16];
    int t = threadIdx.x;

    if (t < 16) {
        float h = 0.f;
#pragma unroll
        for (int jj = 0; jj < 16; jj++)
            h += (psum[b * 16 + jj] * (1.f / 3136.f)) * fc1[jj];
        h = fmaxf(h, 0.f);
        float z = h * fc2[t];
        gg[t] = 1.f / (1.f + __expf(-z));
    }
    {
        const float* sb = s_ws + (size_t)(b * HW + px0) * 16;
#pragma unroll
        for (int i = 0; i < 2; i++) {
            int idx = t + 256 * i;
            sl[(idx >> 4) * 17 + (idx & 15)] = sb[idx];
        }
    }
    __syncthreads();
    {
        float sc = gout[t] * rsqrtf(vout[t] + 1e-5f);
        bo[t] = bout[t] - mout[t] * sc;
        const float* wr = se_Wout + (size_t)t * 16;
#pragma unroll
        for (int k = 0; k < 16; k++)
            wg[t * 20 + k] = wr[k] * gg[k] * sc;
    }
    __syncthreads();

    int px = t & 31, og = t >> 5;
    float4 s0 = *(float4*)&sl[px * 17 + 0];
    float4 s1v = *(float4*)&sl[px * 17 + 4];
    float4 s2v = *(float4*)&sl[px * 17 + 8];
    float4 s3 = *(float4*)&sl[px * 17 + 12];
    float* ob = out + (size_t)b * CC * HW + px0 + px;
#pragma unroll
    for (int oi = 0; oi < 32; oi++) {
        int o = og * 32 + oi;
        float4 w0 = *(float4*)&wg[o * 20 + 0];
        float4 w1 = *(float4*)&wg[o * 20 + 4];
        float4 w2 = *(float4*)&wg[o * 20 + 8];
        float4 w3 = *(float4*)&wg[o * 20 + 12];
        float r = bo[o]
            + s0.x * w0.x + s0.y * w0.y + s0.z * w0.z + s0.w * w0.w
            + s1v.x * w1.x + s1v.y * w1.y + s1v.z * w1.z + s1v.w * w1.w
            + s2v.x * w2.x + s2v.y * w2.y + s2v.z * w2.z + s2v.w * w2.w
            + s3.x * w3.x + s3.y * w3.y + s3.z * w3.z + s3.w * w3.w;
        ob[(size_t)o * HW] = r;
    }
}

extern "C" void kernel_launch(void* const* d_in, const int* in_sizes, int n_in,
                              void* d_out, int out_size, void* d_ws, size_t ws_size,
                              hipStream_t stream) {
    const float* x     = (const float*)d_in[0];
    const float* Wq    = (const float*)d_in[1];
    const float* Wk    = (const float*)d_in[2];
    const float* Wv    = (const float*)d_in[3];
    const float* rel_h = (const float*)d_in[4];
    const float* rel_w = (const float*)d_in[5];
    const float* agg_g1 = (const float*)d_in[6];
    const float* agg_b1 = (const float*)d_in[7];
    const float* agg_m1 = (const float*)d_in[8];
    const float* agg_v1 = (const float*)d_in[9];
    const float* agg_W  = (const float*)d_in[10];
    const float* agg_g2 = (const float*)d_in[11];
    const float* agg_b2 = (const float*)d_in[12];
    const float* agg_m2 = (const float*)d_in[13];
    const float* agg_v2 = (const float*)d_in[14];
    const float* se_Win = (const float*)d_in[15];
    const float* se_g_in = (const float*)d_in[16];
    const float* se_b_in = (const float*)d_in[17];
    const float* se_m_in = (const float*)d_in[18];
    const float* se_v_in = (const float*)d_in[19];
    const float* se_fc1  = (const float*)d_in[20];
    const float* se_fc2  = (const float*)d_in[21];
    const float* se_Wout = (const float*)d_in[22];
    const float* se_g_out = (const float*)d_in[23];
    const float* se_b_out = (const float*)d_in[24];
    const float* se_m_out = (const float*)d_in[25];
    const float* se_v_out = (const float*)d_in[26];

    const size_t NQ = (size_t)BB * HW * CC;   // 3,211,264
    unsigned short* q_ws  = (unsigned short*)d_ws;   // bf16, NQ each
    unsigned short* k_ws  = q_ws + NQ;
    unsigned short* v_ws  = k_ws + NQ;
    unsigned short* ao_ws = v_ws + NQ;
    unsigned short* xt    = ao_ws;                   // alias: xt dead before ao born
    float* y2_ws = (float*)d_ws;                     // alias over q+k (4*NQ bytes)
    float* s_ws  = (float*)(ao_ws + NQ);
    float* psum  = s_ws + (size_t)BB * HW * 16;
    unsigned short* wbf = (unsigned short*)(psum + 64);  // 4x65536 + 4096 bf16

    xt_cvt<<<dim3(49, 4, 4), 256, 0, stream>>>(x, xt);
    wcvt<<<dim3(64, 5), 256, 0, stream>>>(Wq, Wk, Wv, agg_W, se_Win, wbf, psum);
    qkv_mfma<<<dim3(98, 2, 3), 256, 0, stream>>>(xt, wbf, q_ws, k_ws, v_ws);
    attn_kernel<<<dim3(196, 2, 4), 256, 0, stream>>>(q_ws, k_ws, v_ws, rel_h, rel_w, ao_ws);
    agg_mfma<<<dim3(98, 2), 256, 0, stream>>>(ao_ws, wbf + 3 * 65536,
        agg_g1, agg_b1, agg_m1, agg_v1, agg_g2, agg_b2, agg_m2, agg_v2, y2_ws);
    se_in_mfma<<<dim3(196), 256, 0, stream>>>(y2_ws, wbf + 4 * 65536,
        se_g_in, se_b_in, se_m_in, se_v_in, s_ws, psum);
    se_out_kernel<<<dim3(98, 4), 256, 0, stream>>>(s_ws, psum, se_fc1, se_fc2,
        se_Wout, se_g_out, se_b_out, se_m_out, se_v_out, (float*)d_out);
}